// Round 2
// 250.125 us; speedup vs baseline: 1.0329x; 1.0329x over previous
//
#include <hip/hip_runtime.h>

#define NC 5
#define DICE_EPS 1e-7f

typedef unsigned long long u64;
typedef unsigned int u32;
typedef float v4f __attribute__((ext_vector_type(4)));
typedef int   v4i __attribute__((ext_vector_type(4)));

#define BLOCKS 2048
#define GROUPS 4   // 8192 waves * 256 f4/wave * 4 groups = 8,388,608 = n4 (fast path)

// STORE mode workspace: u32 partials[BLOCKS][16] = 128 KiB (plain stores, no init)
//   partials[b][c] = den1[c], [b][5+c] = den2[c], [b][10+c] = num[c], [b][15] = 0
// ATOMIC mode workspace (fallback, 1 KiB, memset first):
//   cnt[c*16] = den1[c], cnt[(5+c)*16] = den2[c], cnt[(10+c)*16] = num[c]

__device__ __forceinline__ void accum4(v4f pf, v4i mv,
                                       u64& A1, u64& A2, u64& AN)
{
    // Packed 8-bit-per-class counters: class c in bits [8c, 8c+8).
    // Bits [40,48) are a trash bin for "prediction != label".
    int p0 = (int)pf.x, p1 = (int)pf.y, p2 = (int)pf.z, p3 = (int)pf.w;
    int s0 = p0 << 3, s1 = p1 << 3, s2 = p2 << 3, s3 = p3 << 3;
    A1 += (1ull << s0) + (1ull << s1) + (1ull << s2) + (1ull << s3);
    A2 += (1ull << (mv.x << 3)) + (1ull << (mv.y << 3)) +
          (1ull << (mv.z << 3)) + (1ull << (mv.w << 3));
    AN += (1ull << (p0 == mv.x ? s0 : 40)) +
          (1ull << (p1 == mv.y ? s1 : 40)) +
          (1ull << (p2 == mv.z ? s2 : 40)) +
          (1ull << (p3 == mv.w ? s3 : 40));
}

#define FLUSH()                                                         \
    do {                                                                \
        _Pragma("unroll")                                               \
        for (int c = 0; c < NC; ++c) {                                  \
            den1[c] += (u32)(A1 >> (8 * c)) & 0xFF;                     \
            den2[c] += (u32)(A2 >> (8 * c)) & 0xFF;                     \
            num [c] += (u32)(AN >> (8 * c)) & 0xFF;                     \
        }                                                               \
        A1 = 0; A2 = 0; AN = 0;                                         \
    } while (0)

template <bool ATOMIC>
__global__ __launch_bounds__(256) void dice_hist_kernel(
    const float* __restrict__ pred_f, const int* __restrict__ mask,
    u32* __restrict__ ws, int n)
{
    u32 den1[NC] = {0, 0, 0, 0, 0};
    u32 den2[NC] = {0, 0, 0, 0, 0};
    u32 num [NC] = {0, 0, 0, 0, 0};

    const int tid = threadIdx.x;
    const int n4  = n >> 2;

    const v4f* __restrict__ p4 = (const v4f*)pred_f;
    const v4i* __restrict__ m4 = (const v4i*)mask;

    u64 A1 = 0, A2 = 0, AN = 0;

    const int totalWaves = (int)(gridDim.x * blockDim.x) >> 6;
    const int gstride    = totalWaves * 256;   // float4 elems per unroll-group sweep

    if (n4 == gstride * GROUPS) {
        // Fast path: each wave owns contiguous 4KB chunks (256 float4), the
        // whole grid sweeps memory in lockstep (DRAM-row friendly).
        // Per-thread voxels = GROUPS*16 = 64 <= 255 -> single flush at end.
        const int W    = ((int)(blockIdx.x * blockDim.x) + tid) >> 6;
        const int lane = tid & 63;
        int base = W * 256 + lane;
        for (int g = 0; g < GROUPS; ++g, base += gstride) {
            // Issue all 8 loads (nt: streaming / no-allocate hint) ...
            v4f a0 = __builtin_nontemporal_load(p4 + base);
            v4f a1 = __builtin_nontemporal_load(p4 + base + 64);
            v4f a2 = __builtin_nontemporal_load(p4 + base + 128);
            v4f a3 = __builtin_nontemporal_load(p4 + base + 192);
            v4i b0 = __builtin_nontemporal_load(m4 + base);
            v4i b1 = __builtin_nontemporal_load(m4 + base + 64);
            v4i b2 = __builtin_nontemporal_load(m4 + base + 128);
            v4i b3 = __builtin_nontemporal_load(m4 + base + 192);
            // ... and forbid the scheduler from sinking any of them below here.
            __builtin_amdgcn_sched_barrier(0);
            accum4(a0, b0, A1, A2, AN);
            accum4(a1, b1, A1, A2, AN);
            accum4(a2, b2, A1, A2, AN);
            accum4(a3, b3, A1, A2, AN);
        }
        FLUSH();
    } else {
        // Generic path: plain grid-stride with periodic flush.
        const int nt = gridDim.x * blockDim.x;
        int i = blockIdx.x * blockDim.x + tid;
        int cin = 0;
        for (; i < n4; i += nt) {
            accum4(p4[i], m4[i], A1, A2, AN);
            cin += 4;
            if (cin >= 224) { FLUSH(); cin = 0; }
        }
        FLUSH();
        for (int j = (n4 << 2) + blockIdx.x * blockDim.x + tid; j < n; j += nt) {
            int p = (int)pred_f[j];
            int m = mask[j];
            #pragma unroll
            for (int c = 0; c < NC; ++c) {
                u32 a = (p == c), b = (m == c);
                den1[c] += a;
                den2[c] += b;
                num [c] += a & b;
            }
        }
    }

    // wave-level butterfly reduce (wave = 64 lanes)
    #pragma unroll
    for (int c = 0; c < NC; ++c) {
        #pragma unroll
        for (int off = 32; off > 0; off >>= 1) {
            den1[c] += __shfl_xor(den1[c], off, 64);
            den2[c] += __shfl_xor(den2[c], off, 64);
            num [c] += __shfl_xor(num [c], off, 64);
        }
    }

    // combine the block's 4 waves in LDS
    __shared__ u32 s_cnt[16];
    if (tid < 16) s_cnt[tid] = 0;
    __syncthreads();

    if ((tid & 63) == 0) {
        #pragma unroll
        for (int c = 0; c < NC; ++c) {
            atomicAdd(&s_cnt[c],          den1[c]);
            atomicAdd(&s_cnt[NC + c],     den2[c]);
            atomicAdd(&s_cnt[2 * NC + c], num [c]);
        }
    }
    __syncthreads();

    if (ATOMIC) {
        // fallback epilogue: 15 global atomics per block into 1 KiB cnt[]
        if (tid < 3 * NC) atomicAdd(&ws[tid * 16], s_cnt[tid]);
    } else {
        // one plain 64B store per block — no global atomics, no pre-zeroing
        if (tid < 16) ws[(blockIdx.x << 4) + tid] = s_cnt[tid];
    }
}

__global__ __launch_bounds__(1024) void dice_final_kernel(
    const u32* __restrict__ partials, int nblocks,
    float* __restrict__ out)
{
    const int tid = threadIdx.x;
    const int c   = tid & 15;   // which counter
    const int g   = tid >> 4;   // 64 row-groups

    // Coalesced: iteration r reads partials[(r)<<4 | c]; across tid this is
    // a contiguous 4KB line per iteration.
    u32 s = 0;
    #pragma unroll 8
    for (int r = g; r < nblocks; r += 64)
        s += partials[(r << 4) + c];

    __shared__ u32 s_lds[1024];
    s_lds[tid] = s;
    __syncthreads();

    if (tid < 16) {
        u32 t = 0;
        #pragma unroll
        for (int gg = 0; gg < 64; ++gg)
            t += s_lds[(gg << 4) + tid];
        s_lds[tid] = t;          // totals land in s_lds[0..15]
    }
    __syncthreads();

    if (tid == 0) {
        float sdice = 0.0f;
        #pragma unroll
        for (int cc = 0; cc < NC; ++cc) {
            float d1 = (float)s_lds[cc];
            float d2 = (float)s_lds[NC + cc];
            float nm = (float)s_lds[2 * NC + cc];
            sdice += 2.0f * ((nm + DICE_EPS) / (d1 + d2 + DICE_EPS));
        }
        out[0] = sdice / (float)NC;
    }
}

__global__ void dice_final_atomic_kernel(const u32* __restrict__ cnt,
                                         float* __restrict__ out)
{
    if (blockIdx.x == 0 && threadIdx.x == 0) {
        float s = 0.0f;
        #pragma unroll
        for (int c = 0; c < NC; ++c) {
            float d1 = (float)cnt[c * 16];
            float d2 = (float)cnt[(NC + c) * 16];
            float nm = (float)cnt[(2 * NC + c) * 16];
            s += 2.0f * ((nm + DICE_EPS) / (d1 + d2 + DICE_EPS));
        }
        out[0] = s / (float)NC;
    }
}

extern "C" void kernel_launch(void* const* d_in, const int* in_sizes, int n_in,
                              void* d_out, int out_size, void* d_ws, size_t ws_size,
                              hipStream_t stream) {
    const float* pred = (const float*)d_in[0];   // "output": float32 labels
    const int*   mask = (const int*)d_in[1];     // "mask": int32 labels
    const int n = in_sizes[0];                   // 128*512*512 = 33,554,432

    u32* ws = (u32*)d_ws;

    if (ws_size >= (size_t)(BLOCKS * 16 * sizeof(u32))) {
        // Preferred: per-block partials (plain stores), wide tree reduce.
        dice_hist_kernel<false><<<BLOCKS, 256, 0, stream>>>(pred, mask, ws, n);
        dice_final_kernel<<<1, 1024, 0, stream>>>(ws, BLOCKS, (float*)d_out);
    } else {
        // Fallback within 1 KiB workspace: memset + global atomics.
        hipMemsetAsync(d_ws, 0, 256 * sizeof(u32), stream);
        dice_hist_kernel<true><<<BLOCKS, 256, 0, stream>>>(pred, mask, ws, n);
        dice_final_atomic_kernel<<<1, 64, 0, stream>>>(ws, (float*)d_out);
    }
}